// Round 1
// baseline (844.910 us; speedup 1.0000x reference)
//
#include <hip/hip_runtime.h>
#include <hip/hip_bf16.h>

typedef short bf16x8 __attribute__((ext_vector_type(8)));
typedef float f32x4 __attribute__((ext_vector_type(4)));

static constexpr int Bb   = 128;
static constexpr int Cin  = 32;
static constexpr int Nn   = 325;
static constexpr int Tt   = 24;
static constexpr int Cout = 64;
static constexpr int VP   = 360;   // padded v length of X rows (bank-friendly: 720B stride)
static constexpr int SVP  = 352;   // K extent for GEMM1 (11 * 32)
static constexpr int WP   = 336;   // padded w (21 * 16)
static constexpr int NWT  = 21;    // w tiles
static constexpr int NKS  = 11;    // K steps GEMM1
static constexpr int HPAD = 136;   // row stride for W/H LDS tiles (272B -> 2-way max)
static constexpr size_t XT_ELEMS  = (size_t)Bb * Tt * Cin * VP;
static constexpr size_t STP_ELEMS = (size_t)4 * WP * SVP;

// ---------------- Kernel P1: build S' bf16, w-major, identity-augmented ----
// stp[e][w][v] = (e==0) ? (v==w) : supports[e-1][v][w], zero padded.
__global__ void build_stp(const float* __restrict__ sup,
                          __hip_bfloat16* __restrict__ stp) {
    int idx = blockIdx.x * 256 + threadIdx.x;
    int total = 4 * WP * SVP;
    if (idx >= total) return;
    int e = idx / (WP * SVP);
    int r = idx % (WP * SVP);
    int w = r / SVP;
    int v = r % SVP;
    float val = 0.f;
    if (e == 0) {
        val = (v == w && v < Nn) ? 1.f : 0.f;
    } else if (v < Nn && w < Nn) {
        val = sup[((size_t)(e - 1) * Nn + v) * Nn + w];
    }
    stp[idx] = __float2bfloat16(val);
}

// ---------------- Kernel P2: x[b][c][v][t] -> xT[(b*T+t)][c][v] bf16 -------
__global__ void transpose_x(const float* __restrict__ x,
                            __hip_bfloat16* __restrict__ xT) {
    __shared__ float ls[64 * 25];           // [vi][t] padded stride 25 (conflict-free)
    int id = blockIdx.x;
    int vt = id % 6;
    int c  = (id / 6) % Cin;
    int b  = id / (6 * Cin);
    int v0 = vt * 64;
    const float* src = x + (size_t)(b * Cin + c) * Nn * Tt;
    for (int i = threadIdx.x; i < 64 * Tt; i += 256) {
        int vi = i / Tt, t = i % Tt;
        int v = v0 + vi;
        ls[vi * 25 + t] = (v < Nn) ? src[(size_t)v * Tt + t] : 0.f;
    }
    __syncthreads();
    for (int j = threadIdx.x; j < 64 * Tt; j += 256) {
        int t = j / 64, vi = j % 64;
        int v = v0 + vi;
        if (v < VP) {
            xT[((size_t)(b * Tt + t) * Cin + c) * VP + v] =
                __float2bfloat16(ls[vi * 25 + t]);
        }
    }
}

// ---------------- Kernel M: per-(b,t) fused H = [X; X*S] ; out = W*H + b ---
__global__ __launch_bounds__(256, 2) void graphconv_main(
    const __hip_bfloat16* __restrict__ xT,
    const __hip_bfloat16* __restrict__ stp,
    const float* __restrict__ W,
    const float* __restrict__ bias,
    float* __restrict__ out) {
    __shared__ __hip_bfloat16 Xs[Cin * VP];          // 23040 B
    __shared__ __hip_bfloat16 Ws[Cout * HPAD];       // 17408 B
    __shared__ __hip_bfloat16 Hs[4 * 16 * HPAD];     // per-wave 16x136, 17408 B
    __shared__ float bias_s[Cout];

    int bt = blockIdx.x;
    int b = bt / Tt, t = bt % Tt;
    int tid = threadIdx.x;

    // stage X (linear copy, 1440 x 16B)
    {
        const uint4* s = (const uint4*)(xT + (size_t)bt * Cin * VP);
        uint4* d = (uint4*)Xs;
        for (int i = tid; i < (Cin * VP * 2) / 16; i += 256) d[i] = s[i];
    }
    // stage W as bf16 with padded stride
    for (int i = tid; i < Cout * 128; i += 256) {
        int o = i >> 7, k = i & 127;
        Ws[o * HPAD + k] = __float2bfloat16(W[i]);
    }
    if (tid < Cout) bias_s[tid] = bias[tid];
    __syncthreads();

    int wid = tid >> 6, lane = tid & 63;
    int cl = lane & 15;         // A-row / B-col within tile
    int kg = lane >> 4;         // k-group (8 elems each)
    int koffb = kg * 8;

    for (int wt = wid; wt < NWT; wt += 4) {
        int w0 = wt * 16;
        f32x4 acc[8] = {};      // [e*2 + mtile]
        const __hip_bfloat16* stpw = stp + (size_t)(w0 + cl) * SVP + koffb;
#pragma unroll
        for (int ks = 0; ks < NKS; ++ks) {
            int ko = ks * 32 + koffb;
            bf16x8 a0 = *(const bf16x8*)&Xs[cl * VP + ko];
            bf16x8 a1 = *(const bf16x8*)&Xs[(16 + cl) * VP + ko];
#pragma unroll
            for (int e = 0; e < 4; ++e) {
                bf16x8 bf = *(const bf16x8*)&stpw[(size_t)e * WP * SVP + ks * 32];
                acc[e * 2 + 0] = __builtin_amdgcn_mfma_f32_16x16x32_bf16(
                    a0, bf, acc[e * 2 + 0], 0, 0, 0);
                acc[e * 2 + 1] = __builtin_amdgcn_mfma_f32_16x16x32_bf16(
                    a1, bf, acc[e * 2 + 1], 0, 0, 0);
            }
        }
        // write H tile (bf16) in [col][row] layout: row = e*32+mt*16+kg*4+r
        __hip_bfloat16* hw = Hs + wid * 16 * HPAD;
#pragma unroll
        for (int i = 0; i < 8; ++i) {
            int e = i >> 1, mt = i & 1;
            int row = e * 32 + mt * 16 + kg * 4;
            union { unsigned short us[4]; uint2 u2; } pk;
#pragma unroll
            for (int r = 0; r < 4; ++r) {
                __hip_bfloat16 h = __float2bfloat16(acc[i][r]);
                pk.us[r] = *reinterpret_cast<unsigned short*>(&h);
            }
            *(uint2*)&hw[cl * HPAD + row] = pk.u2;
        }
        // GEMM2: out_tile = W * H   (K = 128)
        f32x4 acc2[4] = {};
#pragma unroll
        for (int ks = 0; ks < 4; ++ks) {
            bf16x8 hb = *(const bf16x8*)&hw[cl * HPAD + ks * 32 + koffb];
#pragma unroll
            for (int mt = 0; mt < 4; ++mt) {
                bf16x8 wa = *(const bf16x8*)&Ws[(mt * 16 + cl) * HPAD + ks * 32 + koffb];
                acc2[mt] = __builtin_amdgcn_mfma_f32_16x16x32_bf16(
                    wa, hb, acc2[mt], 0, 0, 0);
            }
        }
        // epilogue: bias + store fp32. C layout: col=lane&15, row=kg*4+r
        int w = w0 + cl;
        if (w < Nn) {
#pragma unroll
            for (int mt = 0; mt < 4; ++mt) {
                int ob = mt * 16 + kg * 4;
#pragma unroll
                for (int r = 0; r < 4; ++r) {
                    int o = ob + r;
                    out[(((size_t)b * Cout + o) * Nn + w) * Tt + t] =
                        acc2[mt][r] + bias_s[o];
                }
            }
        }
    }
}

extern "C" void kernel_launch(void* const* d_in, const int* in_sizes, int n_in,
                              void* d_out, int out_size, void* d_ws, size_t ws_size,
                              hipStream_t stream) {
    const float* x    = (const float*)d_in[0];
    const float* sup  = (const float*)d_in[1];
    const float* W    = (const float*)d_in[2];
    const float* bias = (const float*)d_in[3];
    float* out = (float*)d_out;

    // workspace: xT (70.8 MB) then stp (0.95 MB); total ~71.8 MB
    __hip_bfloat16* xT  = (__hip_bfloat16*)d_ws;
    __hip_bfloat16* stp = xT + XT_ELEMS;

    build_stp<<<(int)((STP_ELEMS + 255) / 256), 256, 0, stream>>>(sup, stp);
    transpose_x<<<Bb * Cin * 6, 256, 0, stream>>>(x, xT);
    graphconv_main<<<Bb * Tt, 256, 0, stream>>>(xT, stp, W, bias, out);
}

// Round 2
// 769.793 us; speedup vs baseline: 1.0976x; 1.0976x over previous
//
#include <hip/hip_runtime.h>
#include <hip/hip_bf16.h>

typedef short bf16x8 __attribute__((ext_vector_type(8)));
typedef float f32x4 __attribute__((ext_vector_type(4)));

static constexpr int Bb   = 128;
static constexpr int Cin  = 32;
static constexpr int Nn   = 325;
static constexpr int Tt   = 24;
static constexpr int Cout = 64;
static constexpr int VP   = 360;   // padded v length of X rows (720B stride)
static constexpr int SVP  = 352;   // K extent for GEMM1 (11 * 32)
static constexpr int WP   = 336;   // padded w (21 * 16)
static constexpr int NWT  = 21;    // w tiles
static constexpr int NKS  = 11;    // K steps GEMM1
static constexpr int CT   = Cin * Tt;  // 768 columns of GEMM1
static constexpr int HP2  = 40;    // H row stride (80B: 16B-aligned, 2-way banks max)
static constexpr int WSP  = 136;   // Ws row stride
static constexpr size_t XT_ELEMS  = (size_t)Bb * Tt * Cin * VP;
static constexpr size_t STP_ELEMS = (size_t)4 * WP * SVP;

// ---------------- Kernel P1: build S' bf16, w-major, identity-augmented ----
__global__ void build_stp(const float* __restrict__ sup,
                          __hip_bfloat16* __restrict__ stp) {
    int idx = blockIdx.x * 256 + threadIdx.x;
    int total = 4 * WP * SVP;
    if (idx >= total) return;
    int e = idx / (WP * SVP);
    int r = idx % (WP * SVP);
    int w = r / SVP;
    int v = r % SVP;
    float val = 0.f;
    if (e == 0) {
        val = (v == w && v < Nn) ? 1.f : 0.f;
    } else if (v < Nn && w < Nn) {
        val = sup[((size_t)(e - 1) * Nn + v) * Nn + w];
    }
    stp[idx] = __float2bfloat16(val);
}

// ---------------- Kernel P2: x[b][c][v][t] -> xT[(b*T+t)][c][v] bf16 -------
__global__ void transpose_x(const float* __restrict__ x,
                            __hip_bfloat16* __restrict__ xT) {
    __shared__ float ls[64 * 25];
    int id = blockIdx.x;
    int vt = id % 6;
    int c  = (id / 6) % Cin;
    int b  = id / (6 * Cin);
    int v0 = vt * 64;
    const float* src = x + (size_t)(b * Cin + c) * Nn * Tt;
    for (int i = threadIdx.x; i < 64 * Tt; i += 256) {
        int vi = i / Tt, t = i % Tt;
        int v = v0 + vi;
        ls[vi * 25 + t] = (v < Nn) ? src[(size_t)v * Tt + t] : 0.f;
    }
    __syncthreads();
    for (int j = threadIdx.x; j < 64 * Tt; j += 256) {
        int t = j / 64, vi = j % 64;
        int v = v0 + vi;
        if (v < VP) {
            xT[((size_t)(b * Tt + t) * Cin + c) * VP + v] =
                __float2bfloat16(ls[vi * 25 + t]);
        }
    }
}

// ---------------- Kernel M: block = (b, wtile16); all 24 t in-block --------
// GEMM1 (per e): Y_e[w][ct] = sum_v stp[e][w][v] * xT[b][ct][v]
// H_e in LDS as [(w*24+t)][c]; GEMM2: acc2[o][(w,t)] += W[o][e*32+c]*H_e
__global__ __launch_bounds__(256, 2) void graphconv_main(
    const __hip_bfloat16* __restrict__ xT,
    const __hip_bfloat16* __restrict__ stp,
    const float* __restrict__ W,
    const float* __restrict__ bias,
    float* __restrict__ out) {
    __shared__ __hip_bfloat16 Ws[Cout * WSP];      // 17408 B
    __shared__ __hip_bfloat16 Hs[384 * HP2];       // 30720 B
    __shared__ float bias_s[Cout];

    // bijective chunked XCD swizzle: 2688 = 8 * 336 blocks
    int bid = blockIdx.x;
    int lg  = (bid & 7) * 336 + (bid >> 3);
    int b   = lg / NWT;
    int wt  = lg % NWT;
    int w0  = wt * 16;

    int tid = threadIdx.x;
    // stage W (bf16, padded) + bias
    for (int i = tid; i < Cout * 128; i += 256) {
        int o = i >> 7, k = i & 127;
        Ws[o * WSP + k] = __float2bfloat16(W[i]);
    }
    if (tid < Cout) bias_s[tid] = bias[tid];
    __syncthreads();

    int wid = tid >> 6, lane = tid & 63;
    int cl = lane & 15;
    int kg = lane >> 4;
    int ko8 = kg * 8;

    const __hip_bfloat16* xb = xT + (size_t)b * CT * VP;

    f32x4 acc2[4][6] = {};   // [o-mtile][n2] persistent across e

    for (int e = 0; e < 4; ++e) {
        // ---- GEMM1: acc1[j] = Y_e[16 w][cols (wid*12+j)*16 + cl] ----
        f32x4 acc1[12] = {};
        const __hip_bfloat16* se = stp + ((size_t)e * WP + w0 + cl) * SVP + ko8;
        for (int ks = 0; ks < NKS; ++ks) {
            bf16x8 a = *(const bf16x8*)(se + ks * 32);
#pragma unroll
            for (int j = 0; j < 12; ++j) {
                int ct = (wid * 12 + j) * 16 + cl;
                bf16x8 bf = *(const bf16x8*)(xb + (size_t)ct * VP + ks * 32 + ko8);
                acc1[j] = __builtin_amdgcn_mfma_f32_16x16x32_bf16(a, bf, acc1[j], 0, 0, 0);
            }
        }
        if (e > 0) __syncthreads();   // prior GEMM2 reads of Hs done
        // ---- scatter Y_e -> Hs[(wl*24+t)][c] ----
#pragma unroll
        for (int j = 0; j < 12; ++j) {
            int ct = (wid * 12 + j) * 16 + cl;
            int t = ct >> 5, c = ct & 31;
#pragma unroll
            for (int r = 0; r < 4; ++r) {
                int wl = kg * 4 + r;
                Hs[(wl * 24 + t) * HP2 + c] = __float2bfloat16(acc1[j][r]);
            }
        }
        __syncthreads();
        // ---- GEMM2: acc2 += W[:, e*32..e*32+31] * H_e ----
        bf16x8 a2[4];
#pragma unroll
        for (int mt = 0; mt < 4; ++mt)
            a2[mt] = *(const bf16x8*)&Ws[(mt * 16 + cl) * WSP + e * 32 + ko8];
#pragma unroll
        for (int n2 = 0; n2 < 6; ++n2) {
            int col2 = (wid * 6 + n2) * 16 + cl;
            bf16x8 b2 = *(const bf16x8*)&Hs[col2 * HP2 + ko8];
#pragma unroll
            for (int mt = 0; mt < 4; ++mt)
                acc2[mt][n2] = __builtin_amdgcn_mfma_f32_16x16x32_bf16(
                    a2[mt], b2, acc2[mt][n2], 0, 0, 0);
        }
    }

    // ---- epilogue: coalesced fp32 stores ----
#pragma unroll
    for (int n2 = 0; n2 < 6; ++n2) {
        int col2 = (wid * 6 + n2) * 16 + cl;
        int wl = col2 / 24;
        int t  = col2 - wl * 24;
        int w  = w0 + wl;
        if (w < Nn) {
#pragma unroll
            for (int mt = 0; mt < 4; ++mt) {
                int o = mt * 16 + kg * 4;
                size_t base = ((size_t)(b * Cout + o) * Nn + w) * Tt + t;
#pragma unroll
                for (int r = 0; r < 4; ++r) {
                    out[base + (size_t)r * Nn * Tt] = acc2[mt][n2][r] + bias_s[o + r];
                }
            }
        }
    }
}

extern "C" void kernel_launch(void* const* d_in, const int* in_sizes, int n_in,
                              void* d_out, int out_size, void* d_ws, size_t ws_size,
                              hipStream_t stream) {
    const float* x    = (const float*)d_in[0];
    const float* sup  = (const float*)d_in[1];
    const float* W    = (const float*)d_in[2];
    const float* bias = (const float*)d_in[3];
    float* out = (float*)d_out;

    __hip_bfloat16* xT  = (__hip_bfloat16*)d_ws;
    __hip_bfloat16* stp = xT + XT_ELEMS;

    build_stp<<<(int)((STP_ELEMS + 255) / 256), 256, 0, stream>>>(sup, stp);
    transpose_x<<<Bb * Cin * 6, 256, 0, stream>>>(x, xT);
    graphconv_main<<<Bb * NWT, 256, 0, stream>>>(xT, stp, W, bias, out);
}

// Round 3
// 345.596 us; speedup vs baseline: 2.4448x; 2.2274x over previous
//
#include <hip/hip_runtime.h>
#include <hip/hip_bf16.h>

typedef short bf16x8 __attribute__((ext_vector_type(8)));
typedef float f32x4 __attribute__((ext_vector_type(4)));

static constexpr int Bb   = 128;
static constexpr int Cin  = 32;
static constexpr int Nn   = 325;
static constexpr int Tt   = 24;
static constexpr int Cout = 64;
static constexpr int VP   = 360;   // padded v length of X rows
static constexpr int SVP  = 352;   // K extent for GEMM1 (11 * 32)
static constexpr int WP   = 336;   // padded w (21 * 16)
static constexpr int NWT  = 21;
static constexpr int NKS  = 11;
static constexpr int TH   = 12;    // t per block
static constexpr int HPAD = 136;   // H row stride
static constexpr size_t XT_ELEMS  = (size_t)Bb * Tt * Cin * VP;
static constexpr size_t STP_ELEMS = (size_t)4 * WP * SVP;

// ---------------- P1: build S' bf16, w-major, identity-augmented ----------
__global__ void build_stp(const float* __restrict__ sup,
                          __hip_bfloat16* __restrict__ stp) {
    int idx = blockIdx.x * 256 + threadIdx.x;
    int total = 4 * WP * SVP;
    if (idx >= total) return;
    int e = idx / (WP * SVP);
    int r = idx % (WP * SVP);
    int w = r / SVP;
    int v = r % SVP;
    float val = 0.f;
    if (e == 0) {
        val = (v == w && v < Nn) ? 1.f : 0.f;
    } else if (v < Nn && w < Nn) {
        val = sup[((size_t)(e - 1) * Nn + v) * Nn + w];
    }
    stp[idx] = __float2bfloat16(val);
}

// ---------------- P1b: W fp32 -> bf16 [64][128] ---------------------------
__global__ void build_wb(const float* __restrict__ W,
                         __hip_bfloat16* __restrict__ Wb) {
    int i = blockIdx.x * 256 + threadIdx.x;
    if (i < Cout * 128) Wb[i] = __float2bfloat16(W[i]);
}

// ---------------- P2: x[b][c][v][t] -> xT[(b*T+t)][c][v] bf16 -------------
__global__ void transpose_x(const float* __restrict__ x,
                            __hip_bfloat16* __restrict__ xT) {
    __shared__ float ls[64 * 25];
    int id = blockIdx.x;
    int vt = id % 6;
    int c  = (id / 6) % Cin;
    int b  = id / (6 * Cin);
    int v0 = vt * 64;
    const float* src = x + (size_t)(b * Cin + c) * Nn * Tt;
    for (int i = threadIdx.x; i < 64 * Tt; i += 256) {
        int vi = i / Tt, t = i % Tt;
        int v = v0 + vi;
        ls[vi * 25 + t] = (v < Nn) ? src[(size_t)v * Tt + t] : 0.f;
    }
    __syncthreads();
    for (int j = threadIdx.x; j < 64 * Tt; j += 256) {
        int t = j / 64, vi = j % 64;
        int v = v0 + vi;
        if (v < VP) {
            xT[((size_t)(b * Tt + t) * Cin + c) * VP + v] =
                __float2bfloat16(ls[vi * 25 + t]);
        }
    }
}

// ---------------- M: block = (b, 16w, 12t); X streamed once ---------------
// GEMM1: acc1[e][j] over all 4 e in one K sweep (X read once from L2).
// H[n=(wl*12+tl)][k=(e*32+c)] in LDS; GEMM2 once: out = Wb * H + bias.
__global__ __launch_bounds__(256, 3) void graphconv_main(
    const __hip_bfloat16* __restrict__ xT,
    const __hip_bfloat16* __restrict__ stp,
    const __hip_bfloat16* __restrict__ Wb,
    const float* __restrict__ bias,
    float* __restrict__ out) {
    __shared__ __hip_bfloat16 Hs[192 * HPAD];   // 52224 B -> 3 blocks/CU

    // XCD swizzle: 5376 = 8 * 672; 672/42 = 16 consecutive b per XCD
    int bid = blockIdx.x;
    int lg  = (bid & 7) * 672 + (bid >> 3);
    int b   = lg / 42;
    int r2  = lg % 42;
    int wt  = r2 >> 1, th = r2 & 1;
    int w0  = wt * 16, t0 = th * TH;

    int tid = threadIdx.x, wid = tid >> 6, lane = tid & 63;
    int cl = lane & 15, kg = lane >> 4, ko8 = kg * 8;

    const __hip_bfloat16* xb = xT + (size_t)(b * Tt + t0) * Cin * VP;
    const __hip_bfloat16* sb = stp + (size_t)(w0 + cl) * SVP + ko8;

    // ---- GEMM1: all 4 e at once, batched loads per K step ----
    f32x4 acc1[4][6] = {};
    for (int ks = 0; ks < NKS; ++ks) {
        bf16x8 af[4], xf[6];
#pragma unroll
        for (int e = 0; e < 4; ++e)
            af[e] = *(const bf16x8*)(sb + (size_t)e * WP * SVP + ks * 32);
#pragma unroll
        for (int j = 0; j < 6; ++j) {
            int lc = (wid * 6 + j) * 16 + cl;
            xf[j] = *(const bf16x8*)(xb + (size_t)lc * VP + ks * 32 + ko8);
        }
#pragma unroll
        for (int e = 0; e < 4; ++e)
#pragma unroll
            for (int j = 0; j < 6; ++j)
                acc1[e][j] = __builtin_amdgcn_mfma_f32_16x16x32_bf16(
                    af[e], xf[j], acc1[e][j], 0, 0, 0);
    }

    // ---- scatter Y -> Hs[n][k] ----
#pragma unroll
    for (int e = 0; e < 4; ++e)
#pragma unroll
        for (int j = 0; j < 6; ++j) {
            int lc = (wid * 6 + j) * 16 + cl;
            int tl = lc >> 5, c = lc & 31;
#pragma unroll
            for (int r = 0; r < 4; ++r) {
                int n = (kg * 4 + r) * TH + tl;
                Hs[n * HPAD + e * 32 + c] = __float2bfloat16(acc1[e][j][r]);
            }
        }
    __syncthreads();

    // ---- GEMM2: [64 o] x [K=128] x [N=192] ----
    f32x4 acc2[4][3] = {};
#pragma unroll
    for (int ks2 = 0; ks2 < 4; ++ks2) {
        bf16x8 wf[4], hf[3];
#pragma unroll
        for (int mt = 0; mt < 4; ++mt)
            wf[mt] = *(const bf16x8*)(Wb + (mt * 16 + cl) * 128 + ks2 * 32 + ko8);
#pragma unroll
        for (int nt = 0; nt < 3; ++nt)
            hf[nt] = *(const bf16x8*)&Hs[((wid * 3 + nt) * 16 + cl) * HPAD + ks2 * 32 + ko8];
#pragma unroll
        for (int mt = 0; mt < 4; ++mt)
#pragma unroll
            for (int nt = 0; nt < 3; ++nt)
                acc2[mt][nt] = __builtin_amdgcn_mfma_f32_16x16x32_bf16(
                    wf[mt], hf[nt], acc2[mt][nt], 0, 0, 0);
    }

    // ---- epilogue ----
#pragma unroll
    for (int nt = 0; nt < 3; ++nt) {
        int n = (wid * 3 + nt) * 16 + cl;
        int wl = n / TH, tl = n - wl * TH;
        int w = w0 + wl;
        if (w < Nn) {
#pragma unroll
            for (int mt = 0; mt < 4; ++mt) {
                int o = mt * 16 + kg * 4;
                size_t base = ((size_t)(b * Cout + o) * Nn + w) * Tt + t0 + tl;
#pragma unroll
                for (int r = 0; r < 4; ++r)
                    out[base + (size_t)r * Nn * Tt] = acc2[mt][nt][r] + bias[o + r];
            }
        }
    }
}

extern "C" void kernel_launch(void* const* d_in, const int* in_sizes, int n_in,
                              void* d_out, int out_size, void* d_ws, size_t ws_size,
                              hipStream_t stream) {
    const float* x    = (const float*)d_in[0];
    const float* sup  = (const float*)d_in[1];
    const float* W    = (const float*)d_in[2];
    const float* bias = (const float*)d_in[3];
    float* out = (float*)d_out;

    __hip_bfloat16* xT  = (__hip_bfloat16*)d_ws;
    __hip_bfloat16* stp = xT + XT_ELEMS;
    __hip_bfloat16* Wb  = stp + STP_ELEMS;

    build_stp<<<(int)((STP_ELEMS + 255) / 256), 256, 0, stream>>>(sup, stp);
    build_wb<<<(Cout * 128 + 255) / 256, 256, 0, stream>>>(W, Wb);
    transpose_x<<<Bb * Cin * 6, 256, 0, stream>>>(x, xT);
    graphconv_main<<<Bb * NWT * 2, 256, 0, stream>>>(xT, stp, Wb, bias, out);
}